// Round 7
// baseline (205.615 us; speedup 1.0000x reference)
//
#include <hip/hip_runtime.h>

#define N_NODES 100000
#define N_EDGES 1600000
#define BN_EPS 1e-5f
#define NB 1563       // ceil(100000/64) buckets of 64 nodes
#define CAP 1472      // fixed bucket capacity (mean 1024 + 14 sigma)
#define CH 2048       // edges per binning block

typedef short short8 __attribute__((ext_vector_type(8)));
typedef float floatx4 __attribute__((ext_vector_type(4)));

__device__ __forceinline__ unsigned short f2bf(float f) {
    unsigned int u = __float_as_uint(f);
    unsigned int r = (u + 0x7fffu + ((u >> 16) & 1u)) >> 16;  // RNE
    return (unsigned short)r;
}
__device__ __forceinline__ float bflo(unsigned int v) { return __uint_as_float(v << 16); }
__device__ __forceinline__ float bfhi(unsigned int v) { return __uint_as_float(v & 0xffff0000u); }

// ---------------- LDS-staged binning: edges -> bucket-grouped code words ----------------
// code = src | (local_dst << 17); bucket b's region = [b*CAP, b*CAP + bcnt[b])
__global__ __launch_bounds__(256) void k_bin(const int* __restrict__ ei,
                                             int* __restrict__ bcnt,
                                             unsigned int* __restrict__ binned, int E) {
    __shared__ int hist[2048];
    __shared__ int base[2048];
    __shared__ int gbase[2048];
    __shared__ int warr[256];
    __shared__ unsigned int stage[CH];
    __shared__ unsigned short stb[CH];
    int tid = threadIdx.x;
    int e0 = blockIdx.x * CH;
    int cn = min(CH, E - e0);

    for (int i = tid; i < 2048; i += 256) hist[i] = 0;
    __syncthreads();

    unsigned int mycode[8];
    short myb[8], myslot[8];
    #pragma unroll
    for (int j = 0; j < 8; j++) {
        int idx = j * 256 + tid;
        if (idx < cn) {
            int e = e0 + idx;
            int src = ei[e];
            int dst = ei[E + e];
            int b = dst >> 6;
            mycode[j] = (unsigned int)src | ((unsigned int)(dst & 63) << 17);
            myb[j] = (short)b;
            myslot[j] = (short)atomicAdd(&hist[b], 1);
        } else myb[j] = -1;
    }
    __syncthreads();

    // exclusive scan of hist[2048]: 8 per thread + 256-wide Hillis-Steele
    int h[8], t8 = 0;
    #pragma unroll
    for (int k = 0; k < 8; k++) { h[k] = hist[tid * 8 + k]; t8 += h[k]; }
    warr[tid] = t8;
    __syncthreads();
    for (int o = 1; o < 256; o <<= 1) {
        int x = (tid >= o) ? warr[tid - o] : 0;
        __syncthreads();
        warr[tid] += x;
        __syncthreads();
    }
    int ex = warr[tid] - t8;
    #pragma unroll
    for (int k = 0; k < 8; k++) { base[tid * 8 + k] = ex; ex += h[k]; }
    __syncthreads();

    #pragma unroll
    for (int j = 0; j < 8; j++) {
        if (myb[j] >= 0) {
            int p = base[myb[j]] + myslot[j];
            stage[p] = mycode[j];
            stb[p] = (unsigned short)myb[j];
        }
    }
    for (int b = tid; b < NB; b += 256) {
        int c = hist[b];
        if (c) gbase[b] = b * CAP + atomicAdd(&bcnt[b], c);
    }
    __syncthreads();
    for (int i = tid; i < cn; i += 256) {
        int b = stb[i];
        binned[gbase[b] + (i - base[b])] = stage[i];
    }
}

// ---------------- per-bucket degree histogram -> dinv ----------------
__global__ __launch_bounds__(256) void k_dd(const unsigned int* __restrict__ binned,
                                            const int* __restrict__ bcnt,
                                            float* __restrict__ dinv, int n) {
    __shared__ int hist[64];
    int b = blockIdx.x, t = threadIdx.x;
    int nb0 = b * 64;
    int e0 = b * CAP;
    int cnt = bcnt[b];
    if (t < 64) hist[t] = 0;
    __syncthreads();
    for (int i = t; i < cnt; i += 256)
        atomicAdd(&hist[binned[e0 + i] >> 17], 1);
    __syncthreads();
    int nr = min(64, n - nb0);
    if (t < nr) dinv[nb0 + t] = rsqrtf((float)(hist[t] + 1));
}

// ---------------- W f32 -> bf16 ----------------
__global__ void k_wcvt(const float* __restrict__ Wf, unsigned short* __restrict__ Wb) {
    int i = blockIdx.x * 256 + threadIdx.x;
    if (i < 128 * 128) Wb[i] = f2bf(Wf[i]);
}

// ---------------- GEMM h = x @ W^T via bf16 MFMA, h stored as bf16 ----------------
// 256 thr = 4 waves; each wave owns 32 rows (2 row-tiles of 16); block = 128 rows.
__global__ __launch_bounds__(256) void k_gemm(const float* __restrict__ x,
                                              const unsigned short* __restrict__ Wb,
                                              unsigned short* __restrict__ hb, int n) {
    int w = threadIdx.x >> 6;
    int l = threadIdx.x & 63;
    int rowbase = blockIdx.x * 128 + w * 32;
    int r16 = l & 15;
    int kg = l >> 4;

    short8 a[2][4];
    #pragma unroll
    for (int m = 0; m < 2; m++) {
        int row = rowbase + m * 16 + r16;
        int rca = min(row, n - 1);
        const float* base = x + rca * 128;
        #pragma unroll
        for (int q = 0; q < 4; q++) {
            const float4* xp = (const float4*)(base + q * 32 + kg * 8);
            float4 lo = xp[0], hi = xp[1];
            short8 af;
            af[0] = (short)f2bf(lo.x); af[1] = (short)f2bf(lo.y);
            af[2] = (short)f2bf(lo.z); af[3] = (short)f2bf(lo.w);
            af[4] = (short)f2bf(hi.x); af[5] = (short)f2bf(hi.y);
            af[6] = (short)f2bf(hi.z); af[7] = (short)f2bf(hi.w);
            a[m][q] = af;
        }
    }
    for (int t = 0; t < 8; t++) {
        int col = t * 16 + r16;
        short8 b[4];
        #pragma unroll
        for (int q = 0; q < 4; q++)
            b[q] = *(const short8*)(Wb + col * 128 + q * 32 + kg * 8);

        floatx4 acc[2] = {};
        #pragma unroll
        for (int m = 0; m < 2; m++)
            #pragma unroll
            for (int q = 0; q < 4; q++)
                acc[m] = __builtin_amdgcn_mfma_f32_16x16x32_bf16(a[m][q], b[q], acc[m], 0, 0, 0);

        #pragma unroll
        for (int m = 0; m < 2; m++) {
            #pragma unroll
            for (int r = 0; r < 4; r++) {
                int row = rowbase + m * 16 + kg * 4 + r;
                if (row < n) hb[row * 128 + col] = f2bf(acc[m][r]);
            }
        }
    }
}

// ---------------- fused: per-bucket LDS sort + wave-per-node aggregation + BN stats ----------------
__global__ __launch_bounds__(256) void k_fused(const unsigned int* __restrict__ hp,
        const float* __restrict__ dinv, const int* __restrict__ bcnt,
        const unsigned int* __restrict__ binned, float* __restrict__ out,
        float* __restrict__ sums, float* __restrict__ sumsq, int n) {
    __shared__ int hist[64], hsc[64];
    __shared__ float dl[64];
    __shared__ uint2 sh_edge[CAP];       // {src, nrm bits}
    __shared__ float ps[4][128], pq[4][128];
    int t = threadIdx.x;
    int w = t >> 6, l = t & 63;
    int b = blockIdx.x;
    int nb0 = b * 64;
    int e0 = b * CAP;
    int cnt = bcnt[b];
    int nr = min(64, n - nb0);

    if (t < 64) {
        hist[t] = 0;
        if (t < nr) dl[t] = dinv[nb0 + t];
    }
    __syncthreads();

    // round 1: count + claim slot
    unsigned int mycode[6];
    short myslot[6];
    #pragma unroll
    for (int j = 0; j < 6; j++) {
        int i = j * 256 + t;
        if (i < cnt) {
            unsigned int code = binned[e0 + i];
            mycode[j] = code;
            myslot[j] = (short)atomicAdd(&hist[code >> 17], 1);
        } else myslot[j] = -1;
    }
    __syncthreads();

    // inclusive scan of hist[64]
    if (t < 64) hsc[t] = hist[t];
    __syncthreads();
    for (int o = 1; o < 64; o <<= 1) {
        int x = (t < 64 && t >= o) ? hsc[t - o] : 0;
        __syncthreads();
        if (t < 64) hsc[t] += x;
        __syncthreads();
    }

    // place: per-node edge lists + precomputed norm, packed 8B
    #pragma unroll
    for (int j = 0; j < 6; j++) {
        if (myslot[j] >= 0) {
            unsigned int code = mycode[j];
            int ld = code >> 17;
            int src = code & 0x1FFFF;
            int pos = hsc[ld] - hist[ld] + myslot[j];
            sh_edge[pos] = make_uint2((unsigned int)src,
                                      __float_as_uint(dinv[src] * dl[ld]));
        }
    }
    __syncthreads();

    // aggregation: wave w handles nodes w, w+4, ... ; register accumulate, 8-deep MLP
    float s0 = 0, s1 = 0, q0 = 0, q1 = 0;
    for (int r = w; r < nr; r += 4) {
        int i = nb0 + r;
        float di = dl[r];
        unsigned int sv = hp[i * 64 + l];
        float sn = di * di;
        float ax = bflo(sv) * sn;
        float ay = bfhi(sv) * sn;
        int off = hsc[r] - hist[r];
        int dg = hist[r];
        int e = 0;
        for (; e + 7 < dg; e += 8) {
            unsigned int hv[8]; float nn[8];
            #pragma unroll
            for (int j = 0; j < 8; j++) {
                uint2 ed = sh_edge[off + e + j];
                nn[j] = __uint_as_float(ed.y);
                hv[j] = hp[ed.x * 64 + l];
            }
            #pragma unroll
            for (int j = 0; j < 8; j++) {
                ax += nn[j] * bflo(hv[j]);
                ay += nn[j] * bfhi(hv[j]);
            }
        }
        for (; e < dg; e++) {
            uint2 ed = sh_edge[off + e];
            float nnm = __uint_as_float(ed.y);
            unsigned int hv = hp[ed.x * 64 + l];
            ax += nnm * bflo(hv);
            ay += nnm * bfhi(hv);
        }
        ((float2*)out)[i * 64 + l] = make_float2(ax, ay);
        s0 += ax; q0 += ax * ax;
        s1 += ay; q1 += ay * ay;
    }

    // BN partial stats: thread covers cols (2l, 2l+1)
    ps[w][2 * l] = s0; ps[w][2 * l + 1] = s1;
    pq[w][2 * l] = q0; pq[w][2 * l + 1] = q1;
    __syncthreads();
    if (t < 128) {
        float s = 0, q = 0;
        #pragma unroll
        for (int j = 0; j < 4; j++) { s += ps[j][t]; q += pq[j][t]; }
        atomicAdd(&sums[t], s);
        atomicAdd(&sumsq[t], q);
    }
}

// ---------------- BN normalize + ReLU (in place on f32 out) ----------------
__global__ void k_bn(float* __restrict__ out, const float* __restrict__ sums,
                     const float* __restrict__ sumsq, const float* __restrict__ gamma,
                     const float* __restrict__ beta, int n) {
    int idx = blockIdx.x * 256 + threadIdx.x;
    int total = n * 32;
    if (idx >= total) return;
    int c0 = (idx & 31) * 4;
    float invN = 1.0f / (float)n;
    float4 v = ((const float4*)out)[idx];
    float r[4] = {v.x, v.y, v.z, v.w};
    #pragma unroll
    for (int j = 0; j < 4; j++) {
        int c = c0 + j;
        float mean = sums[c] * invN;
        float var = sumsq[c] * invN - mean * mean;
        float scale = rsqrtf(var + BN_EPS) * gamma[c];
        float o = (r[j] - mean) * scale + beta[c];
        r[j] = fmaxf(o, 0.0f);
    }
    ((float4*)out)[idx] = make_float4(r[0], r[1], r[2], r[3]);
}

extern "C" void kernel_launch(void* const* d_in, const int* in_sizes, int n_in,
                              void* d_out, int out_size, void* d_ws, size_t ws_size,
                              hipStream_t stream) {
    const float* x     = (const float*)d_in[0];
    const int*   ei    = (const int*)d_in[1];     // [2][E]
    const float* W     = (const float*)d_in[2];
    // d_in[3] = b : cancels exactly under training-mode BatchNorm -> unused
    const float* gamma = (const float*)d_in[4];
    const float* beta  = (const float*)d_in[5];
    float* out = (float*)d_out;

    const int n = N_NODES, E = N_EDGES;

    // workspace layout (~35.5 MB)
    unsigned short* hb   = (unsigned short*)d_ws;          // 12.8M bf16 (25.6 MB)
    float* dinv   = (float*)(hb + 12800000);               // 100k f32
    float* sums   = dinv + 100000;                         // 128  (memset region start)
    float* sumsq  = sums + 128;                            // 128
    int*   bcnt   = (int*)(sumsq + 128);                   // NB   (memset region end)
    unsigned short* Wb = (unsigned short*)(bcnt + NB);     // 16384 bf16
    unsigned int* binned = (unsigned int*)(Wb + 16384);    // NB*CAP u32 (9.2 MB)

    hipMemsetAsync(sums, 0, (256 + NB) * sizeof(int), stream);

    k_bin<<<(E + CH - 1) / CH, 256, 0, stream>>>(ei, bcnt, binned, E);
    k_dd<<<NB, 256, 0, stream>>>(binned, bcnt, dinv, n);

    k_wcvt<<<64, 256, 0, stream>>>(W, Wb);
    k_gemm<<<(n + 127) / 128, 256, 0, stream>>>(x, Wb, hb, n);

    k_fused<<<NB, 256, 0, stream>>>((const unsigned int*)hb, dinv, bcnt, binned,
                                    out, sums, sumsq, n);

    k_bn<<<(n * 32 + 255) / 256, 256, 0, stream>>>(out, sums, sumsq, gamma, beta, n);
}

// Round 8
// 165.123 us; speedup vs baseline: 1.2452x; 1.2452x over previous
//
#include <hip/hip_runtime.h>

#define N_NODES 100000
#define N_EDGES 1600000
#define BN_EPS 1e-5f
#define SB 25          // super-buckets of 4096 nodes
#define SCAP 69632     // super capacity (mean 64000 + 22 sigma), 17*4096
#define NBB 800        // SB*32 buckets of 128 nodes
#define CAP 2688       // bucket capacity (mean 2048 + 14 sigma)

typedef short short8 __attribute__((ext_vector_type(8)));
typedef float floatx4 __attribute__((ext_vector_type(4)));

__device__ __forceinline__ unsigned short f2bf(float f) {
    unsigned int u = __float_as_uint(f);
    unsigned int r = (u + 0x7fffu + ((u >> 16) & 1u)) >> 16;  // RNE
    return (unsigned short)r;
}
__device__ __forceinline__ float bflo(unsigned int v) { return __uint_as_float(v << 16); }
__device__ __forceinline__ float bfhi(unsigned int v) { return __uint_as_float(v & 0xffff0000u); }

// ---------------- pass A: edges -> 25 super-buckets (coalesced runs ~164) ----------------
// code = src | (dst_local12 << 17)
__global__ __launch_bounds__(512) void k_binA(const int* __restrict__ ei,
                                              int* __restrict__ scnt,
                                              unsigned int* __restrict__ b1, int E) {
    __shared__ int hist[32], base[32], gbase[32];
    __shared__ unsigned int stage[4096];
    __shared__ unsigned char stb[4096];
    int tid = threadIdx.x;
    int e0 = blockIdx.x * 4096;
    int cn = min(4096, E - e0);
    if (tid < 32) hist[tid] = 0;
    __syncthreads();

    unsigned int mycode[8];
    short myslot[8];
    signed char myb[8];
    #pragma unroll
    for (int j = 0; j < 8; j++) {
        int idx = j * 512 + tid;
        if (idx < cn) {
            int src = ei[e0 + idx];
            int dst = ei[E + e0 + idx];
            int s = dst >> 12;
            mycode[j] = (unsigned int)src | ((unsigned int)(dst & 4095) << 17);
            myb[j] = (signed char)s;
            myslot[j] = (short)atomicAdd(&hist[s], 1);
        } else myb[j] = -1;
    }
    __syncthreads();
    if (tid == 0) {
        int run = 0;
        for (int s = 0; s < SB; s++) { base[s] = run; run += hist[s]; }
    }
    __syncthreads();
    #pragma unroll
    for (int j = 0; j < 8; j++) {
        if (myb[j] >= 0) {
            int p = base[myb[j]] + myslot[j];
            stage[p] = mycode[j];
            stb[p] = (unsigned char)myb[j];
        }
    }
    if (tid < SB && hist[tid]) gbase[tid] = tid * SCAP + atomicAdd(&scnt[tid], hist[tid]);
    __syncthreads();
    for (int i = tid; i < cn; i += 512) {
        int s = stb[i];
        b1[gbase[s] + (i - base[s])] = stage[i];
    }
}

// ---------------- pass B: super-bucket -> 32 buckets of 128 nodes (runs = 128) ----------------
// final code = src | (dst_local7 << 17)
__global__ __launch_bounds__(512) void k_binB(const unsigned int* __restrict__ b1,
                                              const int* __restrict__ scnt,
                                              int* __restrict__ bcnt,
                                              unsigned int* __restrict__ b2) {
    __shared__ int hist[32], base[32], gbase[32];
    __shared__ unsigned int stage[4096];
    __shared__ unsigned char stb[4096];
    int tid = threadIdx.x;
    int s = blockIdx.x / 17;
    int c = blockIdx.x % 17;
    int cnt = scnt[s];
    int e0 = s * SCAP + c * 4096;
    int cn = min(4096, cnt - c * 4096);
    if (tid < 32) hist[tid] = 0;
    __syncthreads();

    unsigned int mycode[8];
    short myslot[8];
    signed char myb[8];
    #pragma unroll
    for (int j = 0; j < 8; j++) {
        int idx = j * 512 + tid;
        if (idx < cn) {
            unsigned int code = b1[e0 + idx];
            int sub = (code >> 24) & 31;          // dst_local12 >> 7
            mycode[j] = code & 0x00FFFFFFu;       // src | dst_local7<<17
            myb[j] = (signed char)sub;
            myslot[j] = (short)atomicAdd(&hist[sub], 1);
        } else myb[j] = -1;
    }
    __syncthreads();
    if (tid == 0) {
        int run = 0;
        for (int k = 0; k < 32; k++) { base[k] = run; run += hist[k]; }
    }
    __syncthreads();
    #pragma unroll
    for (int j = 0; j < 8; j++) {
        if (myb[j] >= 0) {
            int p = base[myb[j]] + myslot[j];
            stage[p] = mycode[j];
            stb[p] = (unsigned char)myb[j];
        }
    }
    if (tid < 32 && hist[tid]) {
        int gb = s * 32 + tid;
        gbase[tid] = gb * CAP + atomicAdd(&bcnt[gb], hist[tid]);
    }
    __syncthreads();
    for (int i = tid; i < cn; i += 512) {
        int sub = stb[i];
        b2[gbase[sub] + (i - base[sub])] = stage[i];
    }
}

// ---------------- per-bucket degree histogram -> dinv ----------------
__global__ __launch_bounds__(256) void k_dd(const unsigned int* __restrict__ binned,
                                            const int* __restrict__ bcnt,
                                            float* __restrict__ dinv, int n) {
    __shared__ int hist[128];
    int b = blockIdx.x, t = threadIdx.x;
    int nb0 = b * 128;
    int e0 = b * CAP;
    int cnt = bcnt[b];
    if (t < 128) hist[t] = 0;
    __syncthreads();
    for (int i = t; i < cnt; i += 256)
        atomicAdd(&hist[binned[e0 + i] >> 17], 1);
    __syncthreads();
    int nr = min(128, n - nb0);
    if (t < nr) dinv[nb0 + t] = rsqrtf((float)(hist[t] + 1));
}

// ---------------- W f32 -> bf16 ----------------
__global__ void k_wcvt(const float* __restrict__ Wf, unsigned short* __restrict__ Wb) {
    int i = blockIdx.x * 256 + threadIdx.x;
    if (i < 128 * 128) Wb[i] = f2bf(Wf[i]);
}

// ---------------- GEMM h = x @ W^T via bf16 MFMA, h stored as bf16 ----------------
__global__ __launch_bounds__(256) void k_gemm(const float* __restrict__ x,
                                              const unsigned short* __restrict__ Wb,
                                              unsigned short* __restrict__ hb, int n) {
    int w = threadIdx.x >> 6;
    int l = threadIdx.x & 63;
    int rowbase = blockIdx.x * 128 + w * 32;
    int r16 = l & 15;
    int kg = l >> 4;

    short8 a[2][4];
    #pragma unroll
    for (int m = 0; m < 2; m++) {
        int row = rowbase + m * 16 + r16;
        int rca = min(row, n - 1);
        const float* base = x + rca * 128;
        #pragma unroll
        for (int q = 0; q < 4; q++) {
            const float4* xp = (const float4*)(base + q * 32 + kg * 8);
            float4 lo = xp[0], hi = xp[1];
            short8 af;
            af[0] = (short)f2bf(lo.x); af[1] = (short)f2bf(lo.y);
            af[2] = (short)f2bf(lo.z); af[3] = (short)f2bf(lo.w);
            af[4] = (short)f2bf(hi.x); af[5] = (short)f2bf(hi.y);
            af[6] = (short)f2bf(hi.z); af[7] = (short)f2bf(hi.w);
            a[m][q] = af;
        }
    }
    for (int t = 0; t < 8; t++) {
        int col = t * 16 + r16;
        short8 b[4];
        #pragma unroll
        for (int q = 0; q < 4; q++)
            b[q] = *(const short8*)(Wb + col * 128 + q * 32 + kg * 8);

        floatx4 acc[2] = {};
        #pragma unroll
        for (int m = 0; m < 2; m++)
            #pragma unroll
            for (int q = 0; q < 4; q++)
                acc[m] = __builtin_amdgcn_mfma_f32_16x16x32_bf16(a[m][q], b[q], acc[m], 0, 0, 0);

        #pragma unroll
        for (int m = 0; m < 2; m++) {
            #pragma unroll
            for (int r = 0; r < 4; r++) {
                int row = rowbase + m * 16 + kg * 4 + r;
                if (row < n) hb[row * 128 + col] = f2bf(acc[m][r]);
            }
        }
    }
}

// ---------------- fused: per-bucket LDS sort + wave-per-node aggregation + BN stats ----------------
__global__ __launch_bounds__(512) void k_fused(const unsigned int* __restrict__ hp,
        const float* __restrict__ dinv, const int* __restrict__ bcnt,
        const unsigned int* __restrict__ binned, float* __restrict__ out,
        float* __restrict__ sums, float* __restrict__ sumsq, int n) {
    __shared__ int hist[128], hsc[128];
    __shared__ float dl[128];
    __shared__ uint2 sh_edge[CAP];       // {src, nrm bits}
    __shared__ float ps[8][128], pq[8][128];
    int t = threadIdx.x;
    int w = t >> 6, l = t & 63;
    int b = blockIdx.x;
    int nb0 = b * 128;
    int e0 = b * CAP;
    int cnt = bcnt[b];
    int nr = min(128, n - nb0);

    if (t < 128) {
        hist[t] = 0;
        if (t < nr) dl[t] = dinv[nb0 + t];
    }
    __syncthreads();

    // round 1: count + claim slot
    unsigned int mycode[6];
    short myslot[6];
    #pragma unroll
    for (int j = 0; j < 6; j++) {
        int i = j * 512 + t;
        if (i < cnt) {
            unsigned int code = binned[e0 + i];
            mycode[j] = code;
            myslot[j] = (short)atomicAdd(&hist[code >> 17], 1);
        } else myslot[j] = -1;
    }
    __syncthreads();

    // inclusive scan of hist[128]
    int v = (t < 128) ? hist[t] : 0;
    if (t < 128) hsc[t] = v;
    __syncthreads();
    for (int o = 1; o < 128; o <<= 1) {
        int x = (t < 128 && t >= o) ? hsc[t - o] : 0;
        __syncthreads();
        if (t < 128) hsc[t] += x;
        __syncthreads();
    }

    // place: per-node edge lists + precomputed norm, packed 8B
    #pragma unroll
    for (int j = 0; j < 6; j++) {
        if (myslot[j] >= 0) {
            unsigned int code = mycode[j];
            int ld = code >> 17;
            int src = code & 0x1FFFF;
            int pos = hsc[ld] - hist[ld] + myslot[j];
            sh_edge[pos] = make_uint2((unsigned int)src,
                                      __float_as_uint(dinv[src] * dl[ld]));
        }
    }
    __syncthreads();

    // aggregation: wave w handles nodes w, w+8, ...; register accumulate, 16-deep MLP
    float s0 = 0, s1 = 0, q0 = 0, q1 = 0;
    for (int r = w; r < nr; r += 8) {
        int i = nb0 + r;
        float di = dl[r];
        unsigned int sv = hp[i * 64 + l];
        float sn = di * di;
        float ax = bflo(sv) * sn;
        float ay = bfhi(sv) * sn;
        int off = hsc[r] - hist[r];
        int dg = hist[r];
        int e = 0;
        for (; e + 15 < dg; e += 16) {
            unsigned int hv[16]; float nn[16];
            #pragma unroll
            for (int j = 0; j < 16; j++) {
                uint2 ed = sh_edge[off + e + j];
                nn[j] = __uint_as_float(ed.y);
                hv[j] = hp[ed.x * 64 + l];
            }
            #pragma unroll
            for (int j = 0; j < 16; j++) {
                ax += nn[j] * bflo(hv[j]);
                ay += nn[j] * bfhi(hv[j]);
            }
        }
        for (; e + 3 < dg; e += 4) {
            unsigned int hv[4]; float nn[4];
            #pragma unroll
            for (int j = 0; j < 4; j++) {
                uint2 ed = sh_edge[off + e + j];
                nn[j] = __uint_as_float(ed.y);
                hv[j] = hp[ed.x * 64 + l];
            }
            #pragma unroll
            for (int j = 0; j < 4; j++) {
                ax += nn[j] * bflo(hv[j]);
                ay += nn[j] * bfhi(hv[j]);
            }
        }
        for (; e < dg; e++) {
            uint2 ed = sh_edge[off + e];
            float nnm = __uint_as_float(ed.y);
            unsigned int hv = hp[ed.x * 64 + l];
            ax += nnm * bflo(hv);
            ay += nnm * bfhi(hv);
        }
        ((float2*)out)[i * 64 + l] = make_float2(ax, ay);
        s0 += ax; q0 += ax * ax;
        s1 += ay; q1 += ay * ay;
    }

    // BN partial stats: thread covers cols (2l, 2l+1)
    ps[w][2 * l] = s0; ps[w][2 * l + 1] = s1;
    pq[w][2 * l] = q0; pq[w][2 * l + 1] = q1;
    __syncthreads();
    if (t < 128) {
        float s = 0, q = 0;
        #pragma unroll
        for (int j = 0; j < 8; j++) { s += ps[j][t]; q += pq[j][t]; }
        atomicAdd(&sums[t], s);
        atomicAdd(&sumsq[t], q);
    }
}

// ---------------- BN normalize + ReLU (in place on f32 out) ----------------
__global__ void k_bn(float* __restrict__ out, const float* __restrict__ sums,
                     const float* __restrict__ sumsq, const float* __restrict__ gamma,
                     const float* __restrict__ beta, int n) {
    int idx = blockIdx.x * 256 + threadIdx.x;
    int total = n * 32;
    if (idx >= total) return;
    int c0 = (idx & 31) * 4;
    float invN = 1.0f / (float)n;
    float4 v = ((const float4*)out)[idx];
    float r[4] = {v.x, v.y, v.z, v.w};
    #pragma unroll
    for (int j = 0; j < 4; j++) {
        int c = c0 + j;
        float mean = sums[c] * invN;
        float var = sumsq[c] * invN - mean * mean;
        float scale = rsqrtf(var + BN_EPS) * gamma[c];
        float o = (r[j] - mean) * scale + beta[c];
        r[j] = fmaxf(o, 0.0f);
    }
    ((float4*)out)[idx] = make_float4(r[0], r[1], r[2], r[3]);
}

extern "C" void kernel_launch(void* const* d_in, const int* in_sizes, int n_in,
                              void* d_out, int out_size, void* d_ws, size_t ws_size,
                              hipStream_t stream) {
    const float* x     = (const float*)d_in[0];
    const int*   ei    = (const int*)d_in[1];     // [2][E]
    const float* W     = (const float*)d_in[2];
    // d_in[3] = b : cancels exactly under training-mode BatchNorm -> unused
    const float* gamma = (const float*)d_in[4];
    const float* beta  = (const float*)d_in[5];
    float* out = (float*)d_out;

    const int n = N_NODES, E = N_EDGES;

    // workspace layout (~42 MB)
    unsigned short* hb   = (unsigned short*)d_ws;          // 12.8M bf16 (25.6 MB)
    float* dinv   = (float*)(hb + 12800000);               // 100k f32
    float* sums   = dinv + 100000;                         // 128  (zero region start)
    float* sumsq  = sums + 128;                            // 128
    int*   bcnt   = (int*)(sumsq + 128);                   // NBB
    int*   scnt   = bcnt + NBB;                            // SB   (zero region end)
    unsigned short* Wb = (unsigned short*)(scnt + SB);     // 16384 bf16
    unsigned int* b1 = (unsigned int*)(Wb + 16384);        // SB*SCAP u32 (7.0 MB)
    unsigned int* b2 = b1 + SB * SCAP;                     // NBB*CAP u32 (8.6 MB)

    hipMemsetAsync(sums, 0, (256 + NBB + SB) * sizeof(int), stream);

    k_binA<<<(E + 4095) / 4096, 512, 0, stream>>>(ei, scnt, b1, E);
    k_binB<<<SB * 17, 512, 0, stream>>>(b1, scnt, bcnt, b2);
    k_dd<<<NBB, 256, 0, stream>>>(b2, bcnt, dinv, n);

    k_wcvt<<<64, 256, 0, stream>>>(W, Wb);
    k_gemm<<<(n + 127) / 128, 256, 0, stream>>>(x, Wb, hb, n);

    k_fused<<<NBB, 512, 0, stream>>>((const unsigned int*)hb, dinv, bcnt, b2,
                                     out, sums, sumsq, n);

    k_bn<<<(n * 32 + 255) / 256, 256, 0, stream>>>(out, sums, sumsq, gamma, beta, n);
}

// Round 9
// 159.637 us; speedup vs baseline: 1.2880x; 1.0344x over previous
//
#include <hip/hip_runtime.h>

#define N_NODES 100000
#define N_EDGES 1600000
#define BN_EPS 1e-5f
#define SB 25          // super-buckets of 4096 nodes
#define SCAP 69632     // super capacity (mean 64000 + 22 sigma), 17*4096
#define NBB 800        // SB*32 buckets of 128 nodes
#define CAP 2688       // bucket capacity (mean 2048 + 14 sigma)

typedef short short8 __attribute__((ext_vector_type(8)));
typedef float floatx4 __attribute__((ext_vector_type(4)));

__device__ __forceinline__ unsigned short f2bf(float f) {
    unsigned int u = __float_as_uint(f);
    unsigned int r = (u + 0x7fffu + ((u >> 16) & 1u)) >> 16;  // RNE
    return (unsigned short)r;
}
__device__ __forceinline__ float bflo(unsigned int v) { return __uint_as_float(v << 16); }
__device__ __forceinline__ float bfhi(unsigned int v) { return __uint_as_float(v & 0xffff0000u); }

// ---------------- pass A: edges -> 25 super-buckets (coalesced runs ~164) ----------------
// code = src | (dst_local12 << 17)
__global__ __launch_bounds__(512) void k_binA(const int* __restrict__ ei,
                                              int* __restrict__ scnt,
                                              unsigned int* __restrict__ b1, int E) {
    __shared__ int hist[32], base[32], gbase[32];
    __shared__ unsigned int stage[4096];
    __shared__ unsigned char stb[4096];
    int tid = threadIdx.x;
    int e0 = blockIdx.x * 4096;
    int cn = min(4096, E - e0);
    if (tid < 32) hist[tid] = 0;
    __syncthreads();

    unsigned int mycode[8];
    short myslot[8];
    signed char myb[8];
    #pragma unroll
    for (int j = 0; j < 8; j++) {
        int idx = j * 512 + tid;
        if (idx < cn) {
            int src = ei[e0 + idx];
            int dst = ei[E + e0 + idx];
            int s = dst >> 12;
            mycode[j] = (unsigned int)src | ((unsigned int)(dst & 4095) << 17);
            myb[j] = (signed char)s;
            myslot[j] = (short)atomicAdd(&hist[s], 1);
        } else myb[j] = -1;
    }
    __syncthreads();
    if (tid == 0) {
        int run = 0;
        for (int s = 0; s < SB; s++) { base[s] = run; run += hist[s]; }
    }
    __syncthreads();
    #pragma unroll
    for (int j = 0; j < 8; j++) {
        if (myb[j] >= 0) {
            int p = base[myb[j]] + myslot[j];
            stage[p] = mycode[j];
            stb[p] = (unsigned char)myb[j];
        }
    }
    if (tid < SB && hist[tid]) gbase[tid] = tid * SCAP + atomicAdd(&scnt[tid], hist[tid]);
    __syncthreads();
    for (int i = tid; i < cn; i += 512) {
        int s = stb[i];
        b1[gbase[s] + (i - base[s])] = stage[i];
    }
}

// ---------------- pass B: super-bucket -> 32 buckets of 128 nodes (runs = 128) ----------------
// final code = src | (dst_local7 << 17)
__global__ __launch_bounds__(512) void k_binB(const unsigned int* __restrict__ b1,
                                              const int* __restrict__ scnt,
                                              int* __restrict__ bcnt,
                                              unsigned int* __restrict__ b2) {
    __shared__ int hist[32], base[32], gbase[32];
    __shared__ unsigned int stage[4096];
    __shared__ unsigned char stb[4096];
    int tid = threadIdx.x;
    int s = blockIdx.x / 17;
    int c = blockIdx.x % 17;
    int cnt = scnt[s];
    int e0 = s * SCAP + c * 4096;
    int cn = min(4096, cnt - c * 4096);
    if (tid < 32) hist[tid] = 0;
    __syncthreads();

    unsigned int mycode[8];
    short myslot[8];
    signed char myb[8];
    #pragma unroll
    for (int j = 0; j < 8; j++) {
        int idx = j * 512 + tid;
        if (idx < cn) {
            unsigned int code = b1[e0 + idx];
            int sub = (code >> 24) & 31;          // dst_local12 >> 7
            mycode[j] = code & 0x00FFFFFFu;       // src | dst_local7<<17
            myb[j] = (signed char)sub;
            myslot[j] = (short)atomicAdd(&hist[sub], 1);
        } else myb[j] = -1;
    }
    __syncthreads();
    if (tid == 0) {
        int run = 0;
        for (int k = 0; k < 32; k++) { base[k] = run; run += hist[k]; }
    }
    __syncthreads();
    #pragma unroll
    for (int j = 0; j < 8; j++) {
        if (myb[j] >= 0) {
            int p = base[myb[j]] + myslot[j];
            stage[p] = mycode[j];
            stb[p] = (unsigned char)myb[j];
        }
    }
    if (tid < 32 && hist[tid]) {
        int gb = s * 32 + tid;
        gbase[tid] = gb * CAP + atomicAdd(&bcnt[gb], hist[tid]);
    }
    __syncthreads();
    for (int i = tid; i < cn; i += 512) {
        int sub = stb[i];
        b2[gbase[sub] + (i - base[sub])] = stage[i];
    }
}

// ---------------- per-bucket degree histogram -> dinv (before GEMM now) ----------------
__global__ __launch_bounds__(256) void k_dd(const unsigned int* __restrict__ binned,
                                            const int* __restrict__ bcnt,
                                            float* __restrict__ dinv, int n) {
    __shared__ int hist[128];
    int b = blockIdx.x, t = threadIdx.x;
    int nb0 = b * 128;
    int e0 = b * CAP;
    int cnt = bcnt[b];
    if (t < 128) hist[t] = 0;
    __syncthreads();
    for (int i = t; i < cnt; i += 256)
        atomicAdd(&hist[binned[e0 + i] >> 17], 1);
    __syncthreads();
    int nr = min(128, n - nb0);
    if (t < nr) dinv[nb0 + t] = rsqrtf((float)(hist[t] + 1));
}

// ---------------- W f32 -> bf16 ----------------
__global__ void k_wcvt(const float* __restrict__ Wf, unsigned short* __restrict__ Wb) {
    int i = blockIdx.x * 256 + threadIdx.x;
    if (i < 128 * 128) Wb[i] = f2bf(Wf[i]);
}

// ---------------- GEMM g = dinv * (x @ W^T) via bf16 MFMA, g stored as bf16 ----------------
__global__ __launch_bounds__(256) void k_gemm(const float* __restrict__ x,
                                              const unsigned short* __restrict__ Wb,
                                              const float* __restrict__ dinv,
                                              unsigned short* __restrict__ gb, int n) {
    int w = threadIdx.x >> 6;
    int l = threadIdx.x & 63;
    int rowbase = blockIdx.x * 128 + w * 32;
    int r16 = l & 15;
    int kg = l >> 4;

    short8 a[2][4];
    float dv[2][4];
    #pragma unroll
    for (int m = 0; m < 2; m++) {
        int row = rowbase + m * 16 + r16;
        int rca = min(row, n - 1);
        const float* base = x + rca * 128;
        #pragma unroll
        for (int q = 0; q < 4; q++) {
            const float4* xp = (const float4*)(base + q * 32 + kg * 8);
            float4 lo = xp[0], hi = xp[1];
            short8 af;
            af[0] = (short)f2bf(lo.x); af[1] = (short)f2bf(lo.y);
            af[2] = (short)f2bf(lo.z); af[3] = (short)f2bf(lo.w);
            af[4] = (short)f2bf(hi.x); af[5] = (short)f2bf(hi.y);
            af[6] = (short)f2bf(hi.z); af[7] = (short)f2bf(hi.w);
            a[m][q] = af;
        }
        // dinv for this lane's 4 store rows (C/D: row = m*16 + kg*4 + r)
        #pragma unroll
        for (int r = 0; r < 4; r++)
            dv[m][r] = dinv[min(rowbase + m * 16 + kg * 4 + r, n - 1)];
    }
    for (int t = 0; t < 8; t++) {
        int col = t * 16 + r16;
        short8 b[4];
        #pragma unroll
        for (int q = 0; q < 4; q++)
            b[q] = *(const short8*)(Wb + col * 128 + q * 32 + kg * 8);

        floatx4 acc[2] = {};
        #pragma unroll
        for (int m = 0; m < 2; m++)
            #pragma unroll
            for (int q = 0; q < 4; q++)
                acc[m] = __builtin_amdgcn_mfma_f32_16x16x32_bf16(a[m][q], b[q], acc[m], 0, 0, 0);

        #pragma unroll
        for (int m = 0; m < 2; m++) {
            #pragma unroll
            for (int r = 0; r < 4; r++) {
                int row = rowbase + m * 16 + kg * 4 + r;
                if (row < n) gb[row * 128 + col] = f2bf(acc[m][r] * dv[m][r]);
            }
        }
    }
}

// ---------------- fused: per-bucket LDS sort + wave-per-node aggregation + BN stats ----------------
// out_i = dinv_i * (g_i + sum_e g_src)
__global__ __launch_bounds__(512) void k_fused(const unsigned int* __restrict__ hp,
        const float* __restrict__ dinv, const int* __restrict__ bcnt,
        const unsigned int* __restrict__ binned, float* __restrict__ out,
        float* __restrict__ sums, float* __restrict__ sumsq, int n) {
    __shared__ int hist[128], hsc[128];
    __shared__ float dl[128];
    __shared__ unsigned int sh_src[CAP];
    __shared__ float ps[8][128], pq[8][128];
    int t = threadIdx.x;
    int w = t >> 6, l = t & 63;
    int b = blockIdx.x;
    int nb0 = b * 128;
    int e0 = b * CAP;
    int cnt = bcnt[b];
    int nr = min(128, n - nb0);

    if (t < 128) {
        hist[t] = 0;
        if (t < nr) dl[t] = dinv[nb0 + t];
    }
    __syncthreads();

    // round 1: count + claim slot
    unsigned int mycode[6];
    short myslot[6];
    #pragma unroll
    for (int j = 0; j < 6; j++) {
        int i = j * 512 + t;
        if (i < cnt) {
            unsigned int code = binned[e0 + i];
            mycode[j] = code;
            myslot[j] = (short)atomicAdd(&hist[code >> 17], 1);
        } else myslot[j] = -1;
    }
    __syncthreads();

    // inclusive scan of hist[128]
    int v = (t < 128) ? hist[t] : 0;
    if (t < 128) hsc[t] = v;
    __syncthreads();
    for (int o = 1; o < 128; o <<= 1) {
        int x = (t < 128 && t >= o) ? hsc[t - o] : 0;
        __syncthreads();
        if (t < 128) hsc[t] += x;
        __syncthreads();
    }

    // place: per-node edge lists (src only, 4B)
    #pragma unroll
    for (int j = 0; j < 6; j++) {
        if (myslot[j] >= 0) {
            unsigned int code = mycode[j];
            int ld = code >> 17;
            int pos = hsc[ld] - hist[ld] + myslot[j];
            sh_src[pos] = code & 0x1FFFF;
        }
    }
    __syncthreads();

    // aggregation: wave w handles nodes w, w+8, ...; pure-add accumulate, 16-deep MLP
    float s0 = 0, s1 = 0, q0 = 0, q1 = 0;
    for (int r = w; r < nr; r += 8) {
        int i = nb0 + r;
        float di = dl[r];
        unsigned int sv = hp[i * 64 + l];   // self term g_i
        float ax = bflo(sv);
        float ay = bfhi(sv);
        int off = hsc[r] - hist[r];
        int dg = hist[r];
        int e = 0;
        for (; e + 15 < dg; e += 16) {
            unsigned int hv[16];
            #pragma unroll
            for (int j = 0; j < 16; j++)
                hv[j] = hp[sh_src[off + e + j] * 64 + l];
            #pragma unroll
            for (int j = 0; j < 16; j++) {
                ax += bflo(hv[j]);
                ay += bfhi(hv[j]);
            }
        }
        for (; e + 3 < dg; e += 4) {
            unsigned int hv[4];
            #pragma unroll
            for (int j = 0; j < 4; j++)
                hv[j] = hp[sh_src[off + e + j] * 64 + l];
            #pragma unroll
            for (int j = 0; j < 4; j++) {
                ax += bflo(hv[j]);
                ay += bfhi(hv[j]);
            }
        }
        for (; e < dg; e++) {
            unsigned int hv = hp[sh_src[off + e] * 64 + l];
            ax += bflo(hv);
            ay += bfhi(hv);
        }
        float v0 = di * ax, v1 = di * ay;
        ((float2*)out)[i * 64 + l] = make_float2(v0, v1);
        s0 += v0; q0 += v0 * v0;
        s1 += v1; q1 += v1 * v1;
    }

    // BN partial stats: thread covers cols (2l, 2l+1)
    ps[w][2 * l] = s0; ps[w][2 * l + 1] = s1;
    pq[w][2 * l] = q0; pq[w][2 * l + 1] = q1;
    __syncthreads();
    if (t < 128) {
        float s = 0, q = 0;
        #pragma unroll
        for (int j = 0; j < 8; j++) { s += ps[j][t]; q += pq[j][t]; }
        atomicAdd(&sums[t], s);
        atomicAdd(&sumsq[t], q);
    }
}

// ---------------- BN normalize + ReLU (in place on f32 out) ----------------
__global__ void k_bn(float* __restrict__ out, const float* __restrict__ sums,
                     const float* __restrict__ sumsq, const float* __restrict__ gamma,
                     const float* __restrict__ beta, int n) {
    int idx = blockIdx.x * 256 + threadIdx.x;
    int total = n * 32;
    if (idx >= total) return;
    int c0 = (idx & 31) * 4;
    float invN = 1.0f / (float)n;
    float4 v = ((const float4*)out)[idx];
    float r[4] = {v.x, v.y, v.z, v.w};
    #pragma unroll
    for (int j = 0; j < 4; j++) {
        int c = c0 + j;
        float mean = sums[c] * invN;
        float var = sumsq[c] * invN - mean * mean;
        float scale = rsqrtf(var + BN_EPS) * gamma[c];
        float o = (r[j] - mean) * scale + beta[c];
        r[j] = fmaxf(o, 0.0f);
    }
    ((float4*)out)[idx] = make_float4(r[0], r[1], r[2], r[3]);
}

extern "C" void kernel_launch(void* const* d_in, const int* in_sizes, int n_in,
                              void* d_out, int out_size, void* d_ws, size_t ws_size,
                              hipStream_t stream) {
    const float* x     = (const float*)d_in[0];
    const int*   ei    = (const int*)d_in[1];     // [2][E]
    const float* W     = (const float*)d_in[2];
    // d_in[3] = b : cancels exactly under training-mode BatchNorm -> unused
    const float* gamma = (const float*)d_in[4];
    const float* beta  = (const float*)d_in[5];
    float* out = (float*)d_out;

    const int n = N_NODES, E = N_EDGES;

    // workspace layout (~42 MB)
    unsigned short* gbuf = (unsigned short*)d_ws;          // 12.8M bf16 (25.6 MB)
    float* dinv   = (float*)(gbuf + 12800000);             // 100k f32
    float* sums   = dinv + 100000;                         // 128  (zero region start)
    float* sumsq  = sums + 128;                            // 128
    int*   bcnt   = (int*)(sumsq + 128);                   // NBB
    int*   scnt   = bcnt + NBB;                            // SB   (zero region end)
    unsigned short* Wb = (unsigned short*)(scnt + SB);     // 16384 bf16
    unsigned int* b1 = (unsigned int*)(Wb + 16384);        // SB*SCAP u32 (7.0 MB)
    unsigned int* b2 = b1 + SB * SCAP;                     // NBB*CAP u32 (8.6 MB)

    hipMemsetAsync(sums, 0, (256 + NBB + SB) * sizeof(int), stream);

    k_binA<<<(E + 4095) / 4096, 512, 0, stream>>>(ei, scnt, b1, E);
    k_binB<<<SB * 17, 512, 0, stream>>>(b1, scnt, bcnt, b2);
    k_dd<<<NBB, 256, 0, stream>>>(b2, bcnt, dinv, n);

    k_wcvt<<<64, 256, 0, stream>>>(W, Wb);
    k_gemm<<<(n + 127) / 128, 256, 0, stream>>>(x, Wb, dinv, gbuf, n);

    k_fused<<<NBB, 512, 0, stream>>>((const unsigned int*)gbuf, dinv, bcnt, b2,
                                     out, sums, sumsq, n);

    k_bn<<<(n * 32 + 255) / 256, 256, 0, stream>>>(out, sums, sumsq, gamma, beta, n);
}